// Round 2
// baseline (1479.366 us; speedup 1.0000x reference)
//
#include <hip/hip_runtime.h>
#include <stdint.h>

#define M_DIM 8192
#define N_DIM 11008
#define K_DIM 4096
#define BM 128
#define BN 128
#define BK 32

typedef __attribute__((ext_vector_type(8))) short bf16x8;   // 8 bf16 = 4 VGPRs
typedef __attribute__((ext_vector_type(4))) float f32x4;

// fp32 -> bf16 round-to-nearest-even
__device__ __forceinline__ unsigned short f2bf(float f) {
  unsigned int u = __float_as_uint(f);
  u += 0x7fffu + ((u >> 16) & 1u);
  return (unsigned short)(u >> 16);
}

// int in {-1,0,1} -> bf16 bits (exact)
__device__ __forceinline__ unsigned short i2bf(int v) {
  return (unsigned short)(__float_as_uint((float)v) >> 16);
}

// async 16B/lane global->LDS (wave-uniform LDS base; HW writes base + lane*16)
__device__ __forceinline__ void async_cp16(const void* g, void* lds_uniform) {
  __builtin_amdgcn_global_load_lds(
      (__attribute__((address_space(1))) void*)(uintptr_t)g,
      (__attribute__((address_space(3))) void*)(uintptr_t)lds_uniform,
      16, 0, 0);
}

// ---- convert kernels ----
__global__ void cvt_x(const float4* __restrict__ x, uint4* __restrict__ xb) {
  size_t i = (size_t)blockIdx.x * 256 + threadIdx.x;   // 8 floats / thread
  float4 a = x[2 * i], b = x[2 * i + 1];
  uint4 o;
  o.x = (unsigned int)f2bf(a.x) | ((unsigned int)f2bf(a.y) << 16);
  o.y = (unsigned int)f2bf(a.z) | ((unsigned int)f2bf(a.w) << 16);
  o.z = (unsigned int)f2bf(b.x) | ((unsigned int)f2bf(b.y) << 16);
  o.w = (unsigned int)f2bf(b.z) | ((unsigned int)f2bf(b.w) << 16);
  xb[i] = o;
}

// weights arrive as int32 (harness converts integer inputs to int)
__global__ void cvt_w(const int4* __restrict__ w, uint4* __restrict__ wb) {
  size_t i = (size_t)blockIdx.x * 256 + threadIdx.x;   // 8 weights / thread
  int4 a = w[2 * i], b = w[2 * i + 1];
  uint4 o;
  o.x = (unsigned int)i2bf(a.x) | ((unsigned int)i2bf(a.y) << 16);
  o.y = (unsigned int)i2bf(a.z) | ((unsigned int)i2bf(a.w) << 16);
  o.z = (unsigned int)i2bf(b.x) | ((unsigned int)i2bf(b.y) << 16);
  o.w = (unsigned int)i2bf(b.z) | ((unsigned int)i2bf(b.w) << 16);
  wb[i] = o;
}

// ---- main GEMM: A (MxK bf16), B (NxK bf16), C = A*B^T * scale + bias ----
__global__ __launch_bounds__(256) void gemm_bf16(
    const unsigned short* __restrict__ A,
    const unsigned short* __restrict__ B,
    const float* __restrict__ bias,
    const float* __restrict__ scale_p,
    float* __restrict__ C)
{
  __shared__ __align__(16) unsigned short As[BM * BK];  // 8 KB, contiguous (no pad: global_load_lds)
  __shared__ __align__(16) unsigned short Bs[BN * BK];

  const unsigned int t = threadIdx.x;
  const unsigned int n0 = blockIdx.x * BN;
  const unsigned int m0 = blockIdx.y * BM;

  const unsigned int lane = t & 63u;
  const unsigned int wave = t >> 6;
  const unsigned int wm = (wave >> 1) * 64u;   // wave tile 64x64, 2x2 arrangement
  const unsigned int wn = (wave & 1u) * 64u;
  const unsigned int fr = lane & 15u;
  const unsigned int fq = lane >> 4;

  // staging: chunk c = t ; row = c>>2 ; kcol = (c&3)*8 ; LDS elem off = c*8
  const unsigned int arow = t >> 2;
  const unsigned int kcol = (t & 3u) * 8u;
  const unsigned short* agp0 = A + (size_t)(m0 + arow) * K_DIM + kcol;
  const unsigned short* agp1 = agp0 + (size_t)64 * K_DIM;
  const unsigned short* bgp0 = B + (size_t)(n0 + arow) * K_DIM + kcol;
  const unsigned short* bgp1 = bgp0 + (size_t)64 * K_DIM;
  unsigned short* alds0 = As + (t & 192u) * 8u;   // wave-uniform base
  unsigned short* alds1 = alds0 + 2048;
  unsigned short* blds0 = Bs + (t & 192u) * 8u;
  unsigned short* blds1 = blds0 + 2048;

  const unsigned short* afp = As + (wm + fr) * BK + fq * 8u;
  const unsigned short* bfp = Bs + (wn + fr) * BK + fq * 8u;

  f32x4 acc[4][4];
#pragma unroll
  for (int i = 0; i < 4; ++i)
#pragma unroll
    for (int j = 0; j < 4; ++j)
      acc[i][j] = (f32x4){0.f, 0.f, 0.f, 0.f};

  for (int kt = 0; kt < K_DIM / BK; ++kt) {
    async_cp16(agp0, alds0);
    async_cp16(agp1, alds1);
    async_cp16(bgp0, blds0);
    async_cp16(bgp1, blds1);
    agp0 += BK; agp1 += BK; bgp0 += BK; bgp1 += BK;
    __syncthreads();   // drains vmcnt -> LDS writes visible

    bf16x8 af[4], bg[4];
#pragma unroll
    for (int mi = 0; mi < 4; ++mi)
      af[mi] = *(const bf16x8*)(afp + mi * 16 * BK);
#pragma unroll
    for (int ni = 0; ni < 4; ++ni)
      bg[ni] = *(const bf16x8*)(bfp + ni * 16 * BK);
#pragma unroll
    for (int mi = 0; mi < 4; ++mi)
#pragma unroll
      for (int ni = 0; ni < 4; ++ni)
        acc[mi][ni] = __builtin_amdgcn_mfma_f32_16x16x32_bf16(af[mi], bg[ni], acc[mi][ni], 0, 0, 0);
    __syncthreads();   // reads done before next stage overwrites
  }

  const float scale = scale_p[0];
#pragma unroll
  for (int ni = 0; ni < 4; ++ni) {
    const unsigned int ng = n0 + wn + ni * 16 + fr;       // col = lane&15
    const float bb = bias[ng];
#pragma unroll
    for (int mi = 0; mi < 4; ++mi) {
      const unsigned int mg = m0 + wm + mi * 16 + fq * 4; // row = quad*4 + reg
      f32x4 v = acc[mi][ni];
#pragma unroll
      for (int r = 0; r < 4; ++r)
        C[(size_t)(mg + r) * N_DIM + ng] = v[r] * scale + bb;
    }
  }
}

// ---- fallback if d_ws too small: convert during staging (no global_load_lds) ----
__global__ __launch_bounds__(256) void gemm_fused(
    const float* __restrict__ X,
    const int* __restrict__ W,          // int32 weights
    const float* __restrict__ bias,
    const float* __restrict__ scale_p,
    float* __restrict__ C)
{
  __shared__ __align__(16) unsigned short As[BM * BK];
  __shared__ __align__(16) unsigned short Bs[BN * BK];

  const unsigned int t = threadIdx.x;
  const unsigned int n0 = blockIdx.x * BN;
  const unsigned int m0 = blockIdx.y * BM;
  const unsigned int lane = t & 63u;
  const unsigned int wave = t >> 6;
  const unsigned int wm = (wave >> 1) * 64u;
  const unsigned int wn = (wave & 1u) * 64u;
  const unsigned int fr = lane & 15u;
  const unsigned int fq = lane >> 4;

  const unsigned short* afp = As + (wm + fr) * BK + fq * 8u;
  const unsigned short* bfp = Bs + (wn + fr) * BK + fq * 8u;
  const unsigned int brow = t >> 1, bcol = (t & 1u) * 16u;

  f32x4 acc[4][4];
#pragma unroll
  for (int i = 0; i < 4; ++i)
#pragma unroll
    for (int j = 0; j < 4; ++j)
      acc[i][j] = (f32x4){0.f, 0.f, 0.f, 0.f};

  for (int kt = 0; kt < K_DIM; kt += BK) {
#pragma unroll
    for (int i = 0; i < 4; ++i) {            // A: 4 chunks of 4 floats
      unsigned int c = t + i * 256;
      unsigned int row = c >> 3, col = (c & 7u) * 4u;
      float4 v = *(const float4*)(X + (size_t)(m0 + row) * K_DIM + kt + col);
      ushort4 o;
      o.x = f2bf(v.x); o.y = f2bf(v.y); o.z = f2bf(v.z); o.w = f2bf(v.w);
      *(ushort4*)(As + row * BK + col) = o;
    }
    {                                        // B: 16 int32 weights per thread
      const int* wp = W + (size_t)(n0 + brow) * K_DIM + kt + bcol;
      int4 a = *(const int4*)(wp);
      int4 b = *(const int4*)(wp + 4);
      int4 c = *(const int4*)(wp + 8);
      int4 d = *(const int4*)(wp + 12);
      uint4 o0, o1;
      o0.x = (unsigned int)i2bf(a.x) | ((unsigned int)i2bf(a.y) << 16);
      o0.y = (unsigned int)i2bf(a.z) | ((unsigned int)i2bf(a.w) << 16);
      o0.z = (unsigned int)i2bf(b.x) | ((unsigned int)i2bf(b.y) << 16);
      o0.w = (unsigned int)i2bf(b.z) | ((unsigned int)i2bf(b.w) << 16);
      o1.x = (unsigned int)i2bf(c.x) | ((unsigned int)i2bf(c.y) << 16);
      o1.y = (unsigned int)i2bf(c.z) | ((unsigned int)i2bf(c.w) << 16);
      o1.z = (unsigned int)i2bf(d.x) | ((unsigned int)i2bf(d.y) << 16);
      o1.w = (unsigned int)i2bf(d.z) | ((unsigned int)i2bf(d.w) << 16);
      *(uint4*)(Bs + brow * BK + bcol)     = o0;
      *(uint4*)(Bs + brow * BK + bcol + 8) = o1;
    }
    __syncthreads();

    bf16x8 af[4], bg[4];
#pragma unroll
    for (int mi = 0; mi < 4; ++mi)
      af[mi] = *(const bf16x8*)(afp + mi * 16 * BK);
#pragma unroll
    for (int ni = 0; ni < 4; ++ni)
      bg[ni] = *(const bf16x8*)(bfp + ni * 16 * BK);
#pragma unroll
    for (int mi = 0; mi < 4; ++mi)
#pragma unroll
      for (int ni = 0; ni < 4; ++ni)
        acc[mi][ni] = __builtin_amdgcn_mfma_f32_16x16x32_bf16(af[mi], bg[ni], acc[mi][ni], 0, 0, 0);
    __syncthreads();
  }

  const float scale = scale_p[0];
#pragma unroll
  for (int ni = 0; ni < 4; ++ni) {
    const unsigned int ng = n0 + wn + ni * 16 + fr;
    const float bb = bias[ng];
#pragma unroll
    for (int mi = 0; mi < 4; ++mi) {
      const unsigned int mg = m0 + wm + mi * 16 + fq * 4;
      f32x4 v = acc[mi][ni];
#pragma unroll
      for (int r = 0; r < 4; ++r)
        C[(size_t)(mg + r) * N_DIM + ng] = v[r] * scale + bb;
    }
  }
}

extern "C" void kernel_launch(void* const* d_in, const int* in_sizes, int n_in,
                              void* d_out, int out_size, void* d_ws, size_t ws_size,
                              hipStream_t stream) {
  const float* x     = (const float*)d_in[0];
  const int*   wq    = (const int*)d_in[1];    // integer inputs arrive as int32
  const float* scale = (const float*)d_in[2];
  const float* bias  = (const float*)d_in[3];
  float* out         = (float*)d_out;

  const size_t xb_elems = (size_t)M_DIM * K_DIM;   // 33.5M
  const size_t wb_elems = (size_t)N_DIM * K_DIM;   // 45.1M
  const size_t need = (xb_elems + wb_elems) * sizeof(unsigned short);  // 150 MiB

  dim3 grid(N_DIM / BN, M_DIM / BM);  // 86 x 64

  if (ws_size >= need) {
    unsigned short* xb = (unsigned short*)d_ws;
    unsigned short* wb = xb + xb_elems;
    cvt_x<<<(unsigned)(xb_elems / (8 * 256)), 256, 0, stream>>>((const float4*)x, (uint4*)xb);
    cvt_w<<<(unsigned)(wb_elems / (8 * 256)), 256, 0, stream>>>((const int4*)wq, (uint4*)wb);
    gemm_bf16<<<grid, 256, 0, stream>>>(xb, wb, bias, scale, out);
  } else {
    gemm_fused<<<grid, 256, 0, stream>>>(x, wq, bias, scale, out);
  }
}

// Round 3
// 1099.445 us; speedup vs baseline: 1.3456x; 1.3456x over previous
//
#include <hip/hip_runtime.h>
#include <stdint.h>

#define M_DIM 8192
#define N_DIM 11008
#define K_DIM 4096
#define BM 128
#define BN 128
#define BKI 64   // K-tile in int8 elements = 64 B per row (same byte geometry as bf16 BK=32)

typedef __attribute__((ext_vector_type(4))) int i32x4;
typedef __attribute__((ext_vector_type(8))) short bf16x8;
typedef __attribute__((ext_vector_type(4))) float f32x4;

__device__ __forceinline__ void async_cp16(const void* g, void* lds_uniform) {
  __builtin_amdgcn_global_load_lds(
      (__attribute__((address_space(1))) void*)(uintptr_t)g,
      (__attribute__((address_space(3))) void*)(uintptr_t)lds_uniform,
      16, 0, 0);
}

__device__ __forceinline__ unsigned short f2bf(float f) {
  unsigned int u = __float_as_uint(f);
  u += 0x7fffu + ((u >> 16) & 1u);
  return (unsigned short)(u >> 16);
}
__device__ __forceinline__ unsigned short i2bf(int v) {
  return (unsigned short)(__float_as_uint((float)v) >> 16);
}

__device__ __forceinline__ int pack4(int a, int b, int c, int d) {
  return (a & 0xFF) | ((b & 0xFF) << 8) | ((c & 0xFF) << 16) | ((d & 0xFF) << 24);
}

// one block per row: row absmax -> quantize to i8 with step = max/127 (no clipping possible)
__global__ __launch_bounds__(256) void quant_x(const float* __restrict__ x,
                                               signed char* __restrict__ xq,
                                               float* __restrict__ row_step) {
  __shared__ float red[256];
  const unsigned int row = blockIdx.x, t = threadIdx.x;
  const float* xr = x + (size_t)row * K_DIM;
  float4 v[4];
#pragma unroll
  for (int j = 0; j < 4; ++j)
    v[j] = *(const float4*)(xr + j * 1024 + t * 4);   // coalesced: lane*16B contiguous

  float m = 0.f;
#pragma unroll
  for (int j = 0; j < 4; ++j) {
    m = fmaxf(m, fmaxf(fmaxf(fabsf(v[j].x), fabsf(v[j].y)),
                       fmaxf(fabsf(v[j].z), fabsf(v[j].w))));
  }
  red[t] = m;
  __syncthreads();
#pragma unroll
  for (int s = 128; s > 0; s >>= 1) {
    if (t < s) red[t] = fmaxf(red[t], red[t + s]);
    __syncthreads();
  }
  const float mx = red[0];
  const float r = (mx > 0.f) ? 127.0f / mx : 0.0f;
  if (t == 0) row_step[row] = (mx > 0.f) ? mx / 127.0f : 0.0f;

  int* out = (int*)(xq + (size_t)row * K_DIM);
#pragma unroll
  for (int j = 0; j < 4; ++j) {
    int q0 = __float2int_rn(v[j].x * r);
    int q1 = __float2int_rn(v[j].y * r);
    int q2 = __float2int_rn(v[j].z * r);
    int q3 = __float2int_rn(v[j].w * r);
    out[j * 256 + t] = pack4(q0, q1, q2, q3);   // coalesced dword stores
  }
}

// int32 weights {-1,0,1} -> i8 (exact)
__global__ __launch_bounds__(256) void quant_w(const int4* __restrict__ w,
                                               int* __restrict__ wq) {
  const size_t base = (size_t)blockIdx.x * 1024 + threadIdx.x;
#pragma unroll
  for (int j = 0; j < 4; ++j) {
    int4 a = w[base + j * 256];
    wq[base + j * 256] = pack4(a.x, a.y, a.z, a.w);
  }
}

// ---- main GEMM: A (MxK i8), B (NxK i8), C = (A*B^T)_i32 * (row_step*w_scale) + bias ----
__global__ __launch_bounds__(256) void gemm_i8(
    const signed char* __restrict__ A,
    const signed char* __restrict__ B,
    const float* __restrict__ row_step,
    const float* __restrict__ bias,
    const float* __restrict__ scale_p,
    float* __restrict__ C)
{
  __shared__ __align__(16) signed char As[BM * BKI];  // 8 KB, contiguous (global_load_lds layout)
  __shared__ __align__(16) signed char Bs[BN * BKI];  // 8 KB

  const unsigned int t = threadIdx.x;
  const unsigned int n0 = blockIdx.x * BN;
  const unsigned int m0 = blockIdx.y * BM;

  const unsigned int lane = t & 63u;
  const unsigned int wave = t >> 6;
  const unsigned int wm = (wave >> 1) * 64u;   // wave tile 64x64, 2x2
  const unsigned int wn = (wave & 1u) * 64u;
  const unsigned int fr = lane & 15u;
  const unsigned int fq = lane >> 4;

  // staging: chunk c = t -> row c>>2, 16B chunk (c&3) within the 64B row
  const unsigned int arow = t >> 2;
  const unsigned int kcol = (t & 3u) * 16u;
  const signed char* agp0 = A + (size_t)(m0 + arow) * K_DIM + kcol;
  const signed char* agp1 = agp0 + (size_t)64 * K_DIM;
  const signed char* bgp0 = B + (size_t)(n0 + arow) * K_DIM + kcol;
  const signed char* bgp1 = bgp0 + (size_t)64 * K_DIM;
  signed char* alds0 = As + (t & 192u) * 16u;   // wave-uniform base (HW adds lane*16)
  signed char* alds1 = alds0 + 4096;
  signed char* blds0 = Bs + (t & 192u) * 16u;
  signed char* blds1 = blds0 + 4096;

  // A-fragment: lane holds 16 i8, m = fr, k = fq*16 + j (contiguous 16B)
  const signed char* afp = As + (wm + fr) * BKI + fq * 16u;
  const signed char* bfp = Bs + (wn + fr) * BKI + fq * 16u;

  i32x4 acc[4][4];
#pragma unroll
  for (int i = 0; i < 4; ++i)
#pragma unroll
    for (int j = 0; j < 4; ++j)
      acc[i][j] = (i32x4){0, 0, 0, 0};

  for (int kt = 0; kt < K_DIM / BKI; ++kt) {   // 64 iterations
    async_cp16(agp0, alds0);
    async_cp16(agp1, alds1);
    async_cp16(bgp0, blds0);
    async_cp16(bgp1, blds1);
    agp0 += BKI; agp1 += BKI; bgp0 += BKI; bgp1 += BKI;
    __syncthreads();   // drains vmcnt -> LDS writes visible

    i32x4 af[4], bg[4];
#pragma unroll
    for (int mi = 0; mi < 4; ++mi)
      af[mi] = *(const i32x4*)(afp + mi * 16 * BKI);
#pragma unroll
    for (int ni = 0; ni < 4; ++ni)
      bg[ni] = *(const i32x4*)(bfp + ni * 16 * BKI);
#pragma unroll
    for (int mi = 0; mi < 4; ++mi)
#pragma unroll
      for (int ni = 0; ni < 4; ++ni)
        acc[mi][ni] = __builtin_amdgcn_mfma_i32_16x16x64_i8(af[mi], bg[ni], acc[mi][ni], 0, 0, 0);
    __syncthreads();   // reads done before next stage overwrites
  }

  const float ws = scale_p[0];
  float rs[4][4];
#pragma unroll
  for (int mi = 0; mi < 4; ++mi) {
    const unsigned int mg = m0 + wm + mi * 16 + fq * 4;
#pragma unroll
    for (int r = 0; r < 4; ++r)
      rs[mi][r] = row_step[mg + r] * ws;
  }
#pragma unroll
  for (int ni = 0; ni < 4; ++ni) {
    const unsigned int ng = n0 + wn + ni * 16 + fr;       // col = lane&15
    const float bb = bias[ng];
#pragma unroll
    for (int mi = 0; mi < 4; ++mi) {
      const unsigned int mg = m0 + wm + mi * 16 + fq * 4; // row = quad*4 + reg
      i32x4 v = acc[mi][ni];
#pragma unroll
      for (int r = 0; r < 4; ++r)
        C[(size_t)(mg + r) * N_DIM + ng] = (float)v[r] * rs[mi][r] + bb;
    }
  }
}

// ---- fallback (ws too small): bf16 fused convert-in-staging (correct, slower) ----
__global__ __launch_bounds__(256) void gemm_fused(
    const float* __restrict__ X,
    const int* __restrict__ W,
    const float* __restrict__ bias,
    const float* __restrict__ scale_p,
    float* __restrict__ C)
{
  __shared__ __align__(16) unsigned short As[BM * 32];
  __shared__ __align__(16) unsigned short Bs[BN * 32];

  const unsigned int t = threadIdx.x;
  const unsigned int n0 = blockIdx.x * BN;
  const unsigned int m0 = blockIdx.y * BM;
  const unsigned int lane = t & 63u;
  const unsigned int wave = t >> 6;
  const unsigned int wm = (wave >> 1) * 64u;
  const unsigned int wn = (wave & 1u) * 64u;
  const unsigned int fr = lane & 15u;
  const unsigned int fq = lane >> 4;

  const unsigned short* afp = As + (wm + fr) * 32 + fq * 8u;
  const unsigned short* bfp = Bs + (wn + fr) * 32 + fq * 8u;
  const unsigned int brow = t >> 1, bcol = (t & 1u) * 16u;

  f32x4 acc[4][4];
#pragma unroll
  for (int i = 0; i < 4; ++i)
#pragma unroll
    for (int j = 0; j < 4; ++j)
      acc[i][j] = (f32x4){0.f, 0.f, 0.f, 0.f};

  for (int kt = 0; kt < K_DIM; kt += 32) {
#pragma unroll
    for (int i = 0; i < 4; ++i) {
      unsigned int c = t + i * 256;
      unsigned int row = c >> 3, col = (c & 7u) * 4u;
      float4 v = *(const float4*)(X + (size_t)(m0 + row) * K_DIM + kt + col);
      ushort4 o;
      o.x = f2bf(v.x); o.y = f2bf(v.y); o.z = f2bf(v.z); o.w = f2bf(v.w);
      *(ushort4*)(As + row * 32 + col) = o;
    }
    {
      const int* wp = W + (size_t)(n0 + brow) * K_DIM + kt + bcol;
      int4 a = *(const int4*)(wp);
      int4 b = *(const int4*)(wp + 4);
      int4 c = *(const int4*)(wp + 8);
      int4 d = *(const int4*)(wp + 12);
      uint4 o0, o1;
      o0.x = (unsigned int)i2bf(a.x) | ((unsigned int)i2bf(a.y) << 16);
      o0.y = (unsigned int)i2bf(a.z) | ((unsigned int)i2bf(a.w) << 16);
      o0.z = (unsigned int)i2bf(b.x) | ((unsigned int)i2bf(b.y) << 16);
      o0.w = (unsigned int)i2bf(b.z) | ((unsigned int)i2bf(b.w) << 16);
      o1.x = (unsigned int)i2bf(c.x) | ((unsigned int)i2bf(c.y) << 16);
      o1.y = (unsigned int)i2bf(c.z) | ((unsigned int)i2bf(c.w) << 16);
      o1.z = (unsigned int)i2bf(d.x) | ((unsigned int)i2bf(d.y) << 16);
      o1.w = (unsigned int)i2bf(d.z) | ((unsigned int)i2bf(d.w) << 16);
      *(uint4*)(Bs + brow * 32 + bcol)     = o0;
      *(uint4*)(Bs + brow * 32 + bcol + 8) = o1;
    }
    __syncthreads();

    bf16x8 af[4], bg[4];
#pragma unroll
    for (int mi = 0; mi < 4; ++mi)
      af[mi] = *(const bf16x8*)(afp + mi * 16 * 32);
#pragma unroll
    for (int ni = 0; ni < 4; ++ni)
      bg[ni] = *(const bf16x8*)(bfp + ni * 16 * 32);
#pragma unroll
    for (int mi = 0; mi < 4; ++mi)
#pragma unroll
      for (int ni = 0; ni < 4; ++ni)
        acc[mi][ni] = __builtin_amdgcn_mfma_f32_16x16x32_bf16(af[mi], bg[ni], acc[mi][ni], 0, 0, 0);
    __syncthreads();
  }

  const float scale = scale_p[0];
#pragma unroll
  for (int ni = 0; ni < 4; ++ni) {
    const unsigned int ng = n0 + wn + ni * 16 + fr;
    const float bb = bias[ng];
#pragma unroll
    for (int mi = 0; mi < 4; ++mi) {
      const unsigned int mg = m0 + wm + mi * 16 + fq * 4;
      f32x4 v = acc[mi][ni];
#pragma unroll
      for (int r = 0; r < 4; ++r)
        C[(size_t)(mg + r) * N_DIM + ng] = v[r] * scale + bb;
    }
  }
}

extern "C" void kernel_launch(void* const* d_in, const int* in_sizes, int n_in,
                              void* d_out, int out_size, void* d_ws, size_t ws_size,
                              hipStream_t stream) {
  const float* x     = (const float*)d_in[0];
  const int*   wq    = (const int*)d_in[1];    // integer inputs arrive as int32
  const float* scale = (const float*)d_in[2];
  const float* bias  = (const float*)d_in[3];
  float* out         = (float*)d_out;

  const size_t xq_bytes = (size_t)M_DIM * K_DIM;       // 33.5 MB
  const size_t wq_bytes = (size_t)N_DIM * K_DIM;       // 45.1 MB
  const size_t rs_bytes = (size_t)M_DIM * sizeof(float);
  const size_t need = xq_bytes + wq_bytes + rs_bytes;  // ~78.7 MB

  dim3 grid(N_DIM / BN, M_DIM / BM);  // 86 x 64

  if (ws_size >= need) {
    signed char* xqp = (signed char*)d_ws;
    signed char* wqp = xqp + xq_bytes;
    float* row_step  = (float*)(xqp + xq_bytes + wq_bytes);
    quant_x<<<M_DIM, 256, 0, stream>>>(x, xqp, row_step);
    quant_w<<<(unsigned)(wq_bytes / (16 * 256)), 256, 0, stream>>>((const int4*)wq, (int*)wqp);
    gemm_i8<<<grid, 256, 0, stream>>>(xqp, wqp, row_step, bias, scale, out);
  } else {
    gemm_fused<<<grid, 256, 0, stream>>>(x, wq, bias, scale, out);
  }
}